// Round 1
// 8421.136 us; speedup vs baseline: 1.4554x; 1.4554x over previous
//
#include <hip/hip_runtime.h>
#include <math.h>

typedef __bf16 bf16;
typedef unsigned short u16;
typedef __bf16 bf16x8 __attribute__((ext_vector_type(8)));
typedef float f32x4 __attribute__((ext_vector_type(4)));

#define T_SEQ 2048
#define NB    2
#define CE    512
#define NH    8
#define HD    64
#define ROWS  4096
#define NBH   16
#define LDT   40   // LDS row stride in bf16 elems (80B) -> conflict-free b128 frag reads

// =====================================================================
// Sniffer: flags[0]=1 if float inputs are fp32 storage (raw or rounded);
//          flags[1]=1 if tokens are int64
// =====================================================================
__global__ __launch_bounds__(256) void sniff(const u16* __restrict__ xs,
                                             const int* __restrict__ toks,
                                             int* __restrict__ flags)
{
  const int tid = threadIdx.x;
  int crazy = 0, ze = 0;
  for (int i = tid; i < 4096; i += 256) {
    int e = (xs[i] >> 7) & 0xFF;
    if (e >= 141) crazy++;                    // impossible for bf16 N(0,1)
    if (((i & 1) == 0) && (xs[i] == 0)) ze++; // fp32 low-half exactly zero
  }
  int zc = 0;
  for (int i = tid; i < 1024; i += 256)
    if (toks[2 * i + 1] == 0) zc++;           // int64 high words are 0
  __shared__ int r1[4], r2[4], r3[4];
#pragma unroll
  for (int o = 32; o; o >>= 1) {
    crazy += __shfl_down(crazy, o); ze += __shfl_down(ze, o); zc += __shfl_down(zc, o);
  }
  if ((tid & 63) == 0) { r1[tid >> 6] = crazy; r2[tid >> 6] = ze; r3[tid >> 6] = zc; }
  __syncthreads();
  if (tid == 0) {
    int c = r1[0] + r1[1] + r1[2] + r1[3];
    int z = r2[0] + r2[1] + r2[2] + r2[3];
    int t = r3[0] + r3[1] + r3[2] + r3[3];
    flags[0] = (z > 1500 || c > 64) ? 1 : 0;
    flags[1] = (t > 900) ? 1 : 0;
  }
}

static __device__ __forceinline__ float ldf(const void* src, size_t eoff, bool f32) {
  return f32 ? ((const float*)src)[eoff] : (float)((const bf16*)src)[eoff];
}

// =====================================================================
// Positional embedding: xf = x + pe (fp32 only)
// =====================================================================
__global__ __launch_bounds__(256) void posembed(const void* __restrict__ xsrc,
                                                const int* __restrict__ toks,
                                                const int* __restrict__ flags,
                                                float* __restrict__ xf)
{
  const bool f32 = flags[0] != 0;
  const bool tok64 = flags[1] != 0;
  const int row = blockIdx.x;
  const int t = row >> 1, b = row & 1;
  const int tix = b * T_SEQ + t;
  const int tok = tok64 ? toks[2 * tix] : toks[tix];
  const int p = (tok != 0) ? (t + 1) : 0;
  const float kf = -0.0361193740f; // -ln(10000)/255
  for (int c = threadIdx.x; c < CE; c += 256) {
    float pe = 0.0f;
    if (p != 0) {
      int i = (c < 256) ? c : (c - 256);
      float freq = expf((float)i * kf);
      float ang = (float)p * freq;
      pe = (c < 256) ? sinf(ang) : cosf(ang);
    }
    xf[(size_t)row * CE + c] = ldf(xsrc, (size_t)row * CE + c, f32) + pe;
  }
}

// =====================================================================
// MFMA GEMM: C[M,N] = A[M,K]*W[N,K]^T + bias (+relu), fp32 out.
// Split-bf16 precision recovery: a = a_hi + a_lo (bf16 each);
//   acc = Ahi*Bhi + Alo*Bhi + Ahi*Blo  (fp32 MFMA accumulate)
// lo-terms skipped (uniform branch) when source storage is already bf16.
// 128x128 tile, 4 waves, each wave 64x64 = 4x4 frags of 16x16x32.
// Requires M%128==0, N%128==0, K%32==0 (true for all call sites).
// =====================================================================
template<bool RELUF>
__global__ __launch_bounds__(256) void gemm_mfma(const void* __restrict__ A, int a_inp,
                                                 const void* __restrict__ Bw, size_t bwOff,
                                                 const void* __restrict__ bias, size_t biasOff,
                                                 const int* __restrict__ flags,
                                                 float* __restrict__ Cf,
                                                 int M, int N, int K)
{
  __shared__ __align__(16) bf16 Ah[128 * LDT];
  __shared__ __align__(16) bf16 Al[128 * LDT];
  __shared__ __align__(16) bf16 Bh[128 * LDT];
  __shared__ __align__(16) bf16 Bl[128 * LDT];
  const int fl = flags[0];
  const bool a_f32 = (a_inp == 0) ? true : (fl != 0);
  const bool b_f32 = (fl != 0);
  const bool aLo = a_f32;   // fp32 source needs a low-order term
  const bool bLo = b_f32;
  const int tid = threadIdx.x;
  const int m0 = blockIdx.y * 128, n0 = blockIdx.x * 128;
  const int srow = tid >> 1;          // 0..127 : tile row staged by this thread
  const int skc  = (tid & 1) * 16;    // 0 or 16 : k-chunk within the 32-wide K step
  const int wid = tid >> 6, lane = tid & 63;
  const int wm = (wid >> 1) * 64, wn = (wid & 1) * 64;   // wave's 64x64 sub-tile
  const int fr = lane & 15;           // fragment row (A) / col (B)
  const int fk = (lane >> 4) * 8;     // fragment k offset
  f32x4 acc[4][4] = {};

  for (int k0 = 0; k0 < K; k0 += 32) {
    __syncthreads();
    // ---------------- stage A ----------------
    {
      float v[16];
      size_t g = (size_t)(m0 + srow) * K + k0 + skc;
      if (a_f32) {
        const float4* p = (const float4*)((const float*)A + g);
#pragma unroll
        for (int q = 0; q < 4; q++) {
          float4 t4 = p[q];
          v[4*q+0] = t4.x; v[4*q+1] = t4.y; v[4*q+2] = t4.z; v[4*q+3] = t4.w;
        }
      } else {
        const uint4* u = (const uint4*)((const bf16*)A + g);
        uint4 u0 = u[0], u1 = u[1];
        const bf16* c0 = (const bf16*)&u0; const bf16* c1 = (const bf16*)&u1;
#pragma unroll
        for (int q = 0; q < 8; q++) { v[q] = (float)c0[q]; v[8+q] = (float)c1[q]; }
      }
      bf16x8 h0, h1, l0, l1;
#pragma unroll
      for (int q = 0; q < 8; q++) {
        bf16 ha = (bf16)v[q], hb = (bf16)v[8+q];
        h0[q] = ha; h1[q] = hb;
        l0[q] = (bf16)(v[q]   - (float)ha);
        l1[q] = (bf16)(v[8+q] - (float)hb);
      }
      *(bf16x8*)&Ah[srow * LDT + skc]     = h0;
      *(bf16x8*)&Ah[srow * LDT + skc + 8] = h1;
      if (aLo) {
        *(bf16x8*)&Al[srow * LDT + skc]     = l0;
        *(bf16x8*)&Al[srow * LDT + skc + 8] = l1;
      }
    }
    // ---------------- stage B ----------------
    {
      float v[16];
      size_t g = bwOff + (size_t)(n0 + srow) * K + k0 + skc;
      if (b_f32) {
        const float4* p = (const float4*)((const float*)Bw + g);
#pragma unroll
        for (int q = 0; q < 4; q++) {
          float4 t4 = p[q];
          v[4*q+0] = t4.x; v[4*q+1] = t4.y; v[4*q+2] = t4.z; v[4*q+3] = t4.w;
        }
      } else {
        const uint4* u = (const uint4*)((const bf16*)Bw + g);
        uint4 u0 = u[0], u1 = u[1];
        const bf16* c0 = (const bf16*)&u0; const bf16* c1 = (const bf16*)&u1;
#pragma unroll
        for (int q = 0; q < 8; q++) { v[q] = (float)c0[q]; v[8+q] = (float)c1[q]; }
      }
      bf16x8 h0, h1, l0, l1;
#pragma unroll
      for (int q = 0; q < 8; q++) {
        bf16 ha = (bf16)v[q], hb = (bf16)v[8+q];
        h0[q] = ha; h1[q] = hb;
        l0[q] = (bf16)(v[q]   - (float)ha);
        l1[q] = (bf16)(v[8+q] - (float)hb);
      }
      *(bf16x8*)&Bh[srow * LDT + skc]     = h0;
      *(bf16x8*)&Bh[srow * LDT + skc + 8] = h1;
      if (bLo) {
        *(bf16x8*)&Bl[srow * LDT + skc]     = l0;
        *(bf16x8*)&Bl[srow * LDT + skc + 8] = l1;
      }
    }
    __syncthreads();
    // ---------------- fragments + MFMA ----------------
    bf16x8 ah[4], bh[4];
#pragma unroll
    for (int i = 0; i < 4; i++) ah[i] = *(const bf16x8*)&Ah[(wm + i*16 + fr) * LDT + fk];
#pragma unroll
    for (int j = 0; j < 4; j++) bh[j] = *(const bf16x8*)&Bh[(wn + j*16 + fr) * LDT + fk];
#pragma unroll
    for (int i = 0; i < 4; i++)
#pragma unroll
      for (int j = 0; j < 4; j++)
        acc[i][j] = __builtin_amdgcn_mfma_f32_16x16x32_bf16(ah[i], bh[j], acc[i][j], 0, 0, 0);
    if (aLo) {
      bf16x8 al[4];
#pragma unroll
      for (int i = 0; i < 4; i++) al[i] = *(const bf16x8*)&Al[(wm + i*16 + fr) * LDT + fk];
#pragma unroll
      for (int i = 0; i < 4; i++)
#pragma unroll
        for (int j = 0; j < 4; j++)
          acc[i][j] = __builtin_amdgcn_mfma_f32_16x16x32_bf16(al[i], bh[j], acc[i][j], 0, 0, 0);
    }
    if (bLo) {
      bf16x8 bl[4];
#pragma unroll
      for (int j = 0; j < 4; j++) bl[j] = *(const bf16x8*)&Bl[(wn + j*16 + fr) * LDT + fk];
#pragma unroll
      for (int i = 0; i < 4; i++)
#pragma unroll
        for (int j = 0; j < 4; j++)
          acc[i][j] = __builtin_amdgcn_mfma_f32_16x16x32_bf16(ah[i], bl[j], acc[i][j], 0, 0, 0);
    }
  }
  // ---------------- epilogue: C/D layout col=lane&15, row=(lane>>4)*4+r ----------------
  const int orow0 = m0 + wm + (lane >> 4) * 4;
  const int ocol0 = n0 + wn + (lane & 15);
#pragma unroll
  for (int j = 0; j < 4; j++) {
    int col = ocol0 + j * 16;
    float bv = ldf(bias, biasOff + col, b_f32);
#pragma unroll
    for (int i = 0; i < 4; i++) {
#pragma unroll
      for (int r = 0; r < 4; r++) {
        float vv = acc[i][j][r] + bv;
        if (RELUF) vv = fmaxf(vv, 0.0f);
        Cf[(size_t)(orow0 + i * 16 + r) * N + col] = vv;
      }
    }
  }
}

// =====================================================================
// Min/max pass: direct scores from projection layout; masked entries are
// explicit zeros (exactly mirrors w*mask). partial[2*bidx] = {min,max}.
// =====================================================================
template<bool MASK>
__global__ __launch_bounds__(256) void mm_direct(const float* __restrict__ qbase, int qld, int qofs0,
                                                 const float* __restrict__ kbase, int kld, int kofs0,
                                                 float* __restrict__ partial)
{
  const int bh = blockIdx.x, t0 = blockIdx.y * 64;
  const int b = bh >> 3, h = bh & 7;
  const int qofs = qofs0 + h * HD, kofs = kofs0 + h * HD;
  __shared__ float qs[64 * 68];
  __shared__ float ks[64 * 68];
  const int tid = threadIdx.x;
#pragma unroll
  for (int it = 0; it < 16; it++) {
    int idx = it * 256 + tid, r = idx >> 6, d = idx & 63;
    qs[r * 68 + d] = qbase[(size_t)((t0 + r) * NB + b) * qld + qofs + d] * 0.125f;
  }
  float mn = 1e30f, mx = -1e30f;
  const int send = MASK ? (t0 + 64) : T_SEQ;
  const int t = tid & 63, sg = tid >> 6;
  for (int s0 = 0; s0 < send; s0 += 64) {
    __syncthreads();
#pragma unroll
    for (int it = 0; it < 16; it++) {
      int idx = it * 256 + tid, r = idx >> 6, d = idx & 63;
      ks[r * 68 + d] = kbase[(size_t)((s0 + r) * NB + b) * kld + kofs + d];
    }
    __syncthreads();
    for (int si = 0; si < 16; si++) {
      int sl = sg * 16 + si, s = s0 + sl;
      float dot = 0.f;
#pragma unroll 8
      for (int d = 0; d < 64; d++) dot += qs[t * 68 + d] * ks[sl * 68 + d];
      float wm = (MASK && s > t0 + t) ? 0.0f : dot;  // w * tril: masked -> exact 0
      mn = fminf(mn, wm); mx = fmaxf(mx, wm);
    }
  }
  __shared__ float rn[4], rx[4];
  const int w = tid >> 6, l = tid & 63;
#pragma unroll
  for (int o = 32; o; o >>= 1) { mn = fminf(mn, __shfl_down(mn, o)); mx = fmaxf(mx, __shfl_down(mx, o)); }
  if (l == 0) { rn[w] = mn; rx[w] = mx; }
  __syncthreads();
  if (tid == 0) {
    int bidx = blockIdx.y * NBH + blockIdx.x;
    partial[2 * bidx]     = fminf(fminf(rn[0], rn[1]), fminf(rn[2], rn[3]));
    partial[2 * bidx + 1] = fmaxf(fmaxf(rx[0], rx[1]), fmaxf(rx[2], rx[3]));
  }
}

// reduce 512 partial pairs -> mmf
__global__ __launch_bounds__(512) void reduce_mm(const float* __restrict__ partial,
                                                 float* __restrict__ mmf)
{
  const int tid = threadIdx.x, w = tid >> 6, l = tid & 63;
  __shared__ float rn[8], rx[8];
  float mn = partial[2 * tid], mx = partial[2 * tid + 1];
#pragma unroll
  for (int o = 32; o; o >>= 1) { mn = fminf(mn, __shfl_down(mn, o)); mx = fmaxf(mx, __shfl_down(mx, o)); }
  if (l == 0) { rn[w] = mn; rx[w] = mx; }
  __syncthreads();
  if (tid == 0) {
    float a = 1e30f, c = -1e30f;
#pragma unroll
    for (int i = 0; i < 8; i++) { a = fminf(a, rn[i]); c = fmaxf(c, rx[i]); }
    mmf[0] = a; mmf[1] = c;
  }
}

// =====================================================================
// Apply pass (direct): w' = (w_m - mn)*inv for EVERY s (incl. masked),
// out = sum_s w' * v.  No affine trick, fp32 throughout.
// =====================================================================
template<bool MASK>
__global__ __launch_bounds__(256) void attn_direct(const float* __restrict__ qbase, int qld, int qofs0,
                                                   const float* __restrict__ kbase, int kld, int kofs0,
                                                   int vofs0,
                                                   const float* __restrict__ mmf,
                                                   float* __restrict__ aout)
{
  const int bh = blockIdx.x, t0 = blockIdx.y * 32;
  const int b = bh >> 3, h = bh & 7;
  const int qofs = qofs0 + h * HD, kofs = kofs0 + h * HD, vofs = vofs0 + h * HD;
  __shared__ float qs[32 * 68];
  __shared__ float ks[64 * 68];
  __shared__ float vs[64 * 68];
  __shared__ float sc[32 * 68];
  const int tid = threadIdx.x;
  const float mn = mmf[0];
  const float inv = 1.0f / (mmf[1] - mmf[0]);
#pragma unroll
  for (int it = 0; it < 8; it++) {
    int idx = it * 256 + tid, r = idx >> 6, d = idx & 63;
    qs[r * 68 + d] = qbase[(size_t)((t0 + r) * NB + b) * qld + qofs + d] * 0.125f;
  }
  float accO[8] = {};
  const int tS = tid & 31, sg = tid >> 5;
  for (int s0 = 0; s0 < T_SEQ; s0 += 64) {   // ALL s — masked entries contribute (0-mn)*inv
    __syncthreads();
#pragma unroll
    for (int it = 0; it < 16; it++) {
      int idx = it * 256 + tid, r = idx >> 6, d = idx & 63;
      size_t rowb = (size_t)((s0 + r) * NB + b) * kld;
      ks[r * 68 + d] = kbase[rowb + kofs + d];
      vs[r * 68 + d] = kbase[rowb + vofs + d];
    }
    __syncthreads();
    for (int si = 0; si < 8; si++) {
      int sl = sg * 8 + si, s = s0 + sl;
      float dot = 0.f;
#pragma unroll 8
      for (int d = 0; d < 64; d++) dot += qs[tS * 68 + d] * ks[sl * 68 + d];
      float wm = (MASK && s > t0 + tS) ? 0.0f : dot;
      sc[tS * 68 + sl] = (wm - mn) * inv;    // explicit normalization of every entry
    }
    __syncthreads();
    for (int sl = 0; sl < 64; sl++) {
      float p = sc[tS * 68 + sl];
#pragma unroll
      for (int j = 0; j < 8; j++) accO[j] += p * vs[sl * 68 + sg * 8 + j];
    }
  }
#pragma unroll
  for (int j = 0; j < 8; j++)
    aout[(size_t)((t0 + tS) * NB + b) * CE + h * HD + sg * 8 + j] = accO[j];
}

// =====================================================================
// LayerNorm(res + y), all fp32; g/b raw inputs (dtype by flag)
// =====================================================================
__global__ __launch_bounds__(256) void ln32(const float* res, const float* yy,
                                            const void* __restrict__ g, const void* __restrict__ be,
                                            size_t goff, const int* __restrict__ flags,
                                            float* xfo)
{
  __shared__ float red[4];
  const bool fl = flags[0] != 0;
  const int tid = threadIdx.x;
  const size_t base = (size_t)blockIdx.x * CE;
  float a  = res[base + tid] + yy[base + tid];
  float b2 = res[base + tid + 256] + yy[base + tid + 256];
  float s = a + b2;
#pragma unroll
  for (int o = 32; o; o >>= 1) s += __shfl_down(s, o);
  if ((tid & 63) == 0) red[tid >> 6] = s;
  __syncthreads();
  float mu = (red[0] + red[1] + red[2] + red[3]) * (1.0f / 512.0f);
  __syncthreads();
  float da = a - mu, db = b2 - mu;
  float q = da * da + db * db;
#pragma unroll
  for (int o = 32; o; o >>= 1) q += __shfl_down(q, o);
  if ((tid & 63) == 0) red[tid >> 6] = q;
  __syncthreads();
  float var = (red[0] + red[1] + red[2] + red[3]) * (1.0f / 512.0f);
  float rs = rsqrtf(var + 1e-20f);
  xfo[base + tid]       = da * rs * ldf(g, goff + tid, fl)       + ldf(be, goff + tid, fl);
  xfo[base + tid + 256] = db * rs * ldf(g, goff + tid + 256, fl) + ldf(be, goff + tid + 256, fl);
}

// =====================================================================
extern "C" void kernel_launch(void* const* d_in, const int* in_sizes, int n_in,
                              void* d_out, int out_size, void* d_ws, size_t ws_size,
                              hipStream_t stream)
{
  (void)in_sizes; (void)n_in; (void)out_size; (void)ws_size;
  // dict order (confirmed: in_sizes[0] == 2097152 = x)
  const void* x_in   = d_in[0];
  const void* enc_in = d_in[1];
  const int*  tokens = (const int*)d_in[2];
  const void* sWqkv = d_in[3];
  const void* sbqkv = d_in[4];
  const void* sWo   = d_in[5];
  const void* sbo   = d_in[6];
  const void* cWqkv = d_in[7];
  const void* cbqkv = d_in[8];
  const void* cWo   = d_in[9];
  const void* cbo   = d_in[10];
  const void* fc1w  = d_in[11];
  const void* fc1b  = d_in[12];
  const void* fc2w  = d_in[13];
  const void* fc2b  = d_in[14];
  const void* ln1g  = d_in[15];
  const void* ln1b  = d_in[16];
  const void* ln2g  = d_in[17];
  const void* ln2b  = d_in[18];
  const void* ln3g  = d_in[19];
  const void* ln3b  = d_in[20];

  char* ws = (char*)d_ws;
  size_t off = 0;
  auto alloc = [&](size_t bytes) -> char* {
    char* p = ws + off;
    off += (bytes + 255) & ~(size_t)255;
    return p;
  };
  // total ~40.3 MiB (proven-finite footprint)
  int*   flags   = (int*)  alloc(256);
  float* mmf     = (float*)alloc(256);
  float* partial = (float*)alloc(4096);
  float* xf      = (float*)alloc((size_t)ROWS * CE * 4);      //  8 MiB residual / x
  float* y       = (float*)alloc((size_t)ROWS * CE * 4);      //  8 MiB attn-out / ffn-out
  float* qkv     = (float*)alloc((size_t)ROWS * 1536 * 4);    // 24 MiB projections / h
  float* kvb = qkv + (size_t)ROWS * 512;

  sniff<<<1, 256, 0, stream>>>((const u16*)x_in, tokens, flags);
  posembed<<<ROWS, 256, 0, stream>>>(x_in, tokens, flags, xf);

  for (int l = 0; l < 4; l++) {
    // ---------------- self-attention ----------------
    gemm_mfma<false><<<dim3(12, 32), 256, 0, stream>>>(
        xf, 0, sWqkv, (size_t)l * 1536 * 512, sbqkv, (size_t)l * 1536, flags, qkv, ROWS, 1536, 512);
    mm_direct<true><<<dim3(NBH, 32), 256, 0, stream>>>(qkv, 1536, 0, qkv, 1536, 512, partial);
    reduce_mm<<<1, 512, 0, stream>>>(partial, mmf);
    attn_direct<true><<<dim3(NBH, 64), 256, 0, stream>>>(qkv, 1536, 0, qkv, 1536, 512, 1024, mmf, y);
    gemm_mfma<false><<<dim3(4, 32), 256, 0, stream>>>(
        y, 0, sWo, (size_t)l * 512 * 512, sbo, (size_t)l * 512, flags, qkv, ROWS, 512, 512);
    ln32<<<ROWS, 256, 0, stream>>>(xf, qkv, ln1g, ln1b, (size_t)l * 512, flags, xf);

    // ---------------- cross-attention ----------------
    gemm_mfma<false><<<dim3(4, 32), 256, 0, stream>>>(
        xf, 0, cWqkv, (size_t)l * 1536 * 512, cbqkv, (size_t)l * 1536, flags, qkv, ROWS, 512, 512);
    gemm_mfma<false><<<dim3(8, 32), 256, 0, stream>>>(
        enc_in, 1, cWqkv, (size_t)l * 1536 * 512 + (size_t)512 * 512, cbqkv, (size_t)l * 1536 + 512,
        flags, kvb, ROWS, 1024, 512);
    mm_direct<false><<<dim3(NBH, 32), 256, 0, stream>>>(qkv, 512, 0, kvb, 1024, 0, partial);
    reduce_mm<<<1, 512, 0, stream>>>(partial, mmf);
    attn_direct<false><<<dim3(NBH, 64), 256, 0, stream>>>(qkv, 512, 0, kvb, 1024, 0, 512, mmf, y);
    gemm_mfma<false><<<dim3(4, 32), 256, 0, stream>>>(
        y, 0, cWo, (size_t)l * 512 * 512, cbo, (size_t)l * 512, flags, qkv, ROWS, 512, 512);
    ln32<<<ROWS, 256, 0, stream>>>(xf, qkv, ln2g, ln2b, (size_t)l * 512, flags, xf);

    // ---------------- FFN (two row-halves; h = 16 MiB in qkv) ----------------
    for (int half = 0; half < 2; half++) {
      const float* Ain = xf + (size_t)half * 2048 * 512;
      float* yout = y + (size_t)half * 2048 * 512;
      gemm_mfma<true><<<dim3(16, 16), 256, 0, stream>>>(
          Ain, 0, fc1w, (size_t)l * 2048 * 512, fc1b, (size_t)l * 2048, flags, qkv, 2048, 2048, 512);
      gemm_mfma<false><<<dim3(4, 16), 256, 0, stream>>>(
          qkv, 0, fc2w, (size_t)l * 512 * 2048, fc2b, (size_t)l * 512, flags, yout, 2048, 512, 2048);
    }
    // last layer writes fp32 straight to d_out (reference output dtype = float32)
    float* lnout = (l == 3) ? (float*)d_out : xf;
    ln32<<<ROWS, 256, 0, stream>>>(xf, y, ln3g, ln3b, (size_t)l * 512, flags, lnout);
  }
}

// Round 2
// 3045.633 us; speedup vs baseline: 4.0243x; 2.7650x over previous
//
#include <hip/hip_runtime.h>
#include <math.h>

typedef __bf16 bf16;
typedef unsigned short u16;
typedef __bf16 bf16x8 __attribute__((ext_vector_type(8)));
typedef float f32x4 __attribute__((ext_vector_type(4)));

#define T_SEQ 2048
#define NB    2
#define CE    512
#define NH    8
#define HD    64
#define ROWS  4096
#define NBH   16
#define LDT   40   // GEMM LDS stride (32+8)
#define LDA   72   // attn LDS stride (64+8)

#define MFMA16(a,b,c) __builtin_amdgcn_mfma_f32_16x16x32_bf16((a),(b),(c),0,0,0)

// =====================================================================
// Sniffer: flags[0]=1 if float inputs are fp32 storage; flags[1]=1 if tokens int64
// =====================================================================
__global__ __launch_bounds__(256) void sniff(const u16* __restrict__ xs,
                                             const int* __restrict__ toks,
                                             int* __restrict__ flags)
{
  const int tid = threadIdx.x;
  int crazy = 0, ze = 0;
  for (int i = tid; i < 4096; i += 256) {
    int e = (xs[i] >> 7) & 0xFF;
    if (e >= 141) crazy++;
    if (((i & 1) == 0) && (xs[i] == 0)) ze++;
  }
  int zc = 0;
  for (int i = tid; i < 1024; i += 256)
    if (toks[2 * i + 1] == 0) zc++;
  __shared__ int r1[4], r2[4], r3[4];
#pragma unroll
  for (int o = 32; o; o >>= 1) {
    crazy += __shfl_down(crazy, o); ze += __shfl_down(ze, o); zc += __shfl_down(zc, o);
  }
  if ((tid & 63) == 0) { r1[tid >> 6] = crazy; r2[tid >> 6] = ze; r3[tid >> 6] = zc; }
  __syncthreads();
  if (tid == 0) {
    int c = r1[0] + r1[1] + r1[2] + r1[3];
    int z = r2[0] + r2[1] + r2[2] + r2[3];
    int t = r3[0] + r3[1] + r3[2] + r3[3];
    flags[0] = (z > 1500 || c > 64) ? 1 : 0;
    flags[1] = (t > 900) ? 1 : 0;
  }
}

static __device__ __forceinline__ float ldf(const void* src, size_t eoff, bool f32) {
  return f32 ? ((const float*)src)[eoff] : (float)((const bf16*)src)[eoff];
}

// =====================================================================
// Positional embedding
// =====================================================================
__global__ __launch_bounds__(256) void posembed(const void* __restrict__ xsrc,
                                                const int* __restrict__ toks,
                                                const int* __restrict__ flags,
                                                float* __restrict__ xf)
{
  const bool f32 = flags[0] != 0;
  const bool tok64 = flags[1] != 0;
  const int row = blockIdx.x;
  const int t = row >> 1, b = row & 1;
  const int tix = b * T_SEQ + t;
  const int tok = tok64 ? toks[2 * tix] : toks[tix];
  const int p = (tok != 0) ? (t + 1) : 0;
  const float kf = -0.0361193740f;
  for (int c = threadIdx.x; c < CE; c += 256) {
    float pe = 0.0f;
    if (p != 0) {
      int i = (c < 256) ? c : (c - 256);
      float freq = expf((float)i * kf);
      float ang = (float)p * freq;
      pe = (c < 256) ? sinf(ang) : cosf(ang);
    }
    xf[(size_t)row * CE + c] = ldf(xsrc, (size_t)row * CE + c, f32) + pe;
  }
}

// =====================================================================
// MFMA GEMM (proven in round 1): split-bf16 3-term, 128x128 tile.
// =====================================================================
template<bool RELUF>
__global__ __launch_bounds__(256) void gemm_mfma(const void* __restrict__ A, int a_inp,
                                                 const void* __restrict__ Bw, size_t bwOff,
                                                 const void* __restrict__ bias, size_t biasOff,
                                                 const int* __restrict__ flags,
                                                 float* __restrict__ Cf,
                                                 int M, int N, int K)
{
  __shared__ __align__(16) bf16 Ah[128 * LDT];
  __shared__ __align__(16) bf16 Al[128 * LDT];
  __shared__ __align__(16) bf16 Bh[128 * LDT];
  __shared__ __align__(16) bf16 Bl[128 * LDT];
  const int fl = flags[0];
  const bool a_f32 = (a_inp == 0) ? true : (fl != 0);
  const bool b_f32 = (fl != 0);
  const bool aLo = a_f32;
  const bool bLo = b_f32;
  const int tid = threadIdx.x;
  const int m0 = blockIdx.y * 128, n0 = blockIdx.x * 128;
  const int srow = tid >> 1;
  const int skc  = (tid & 1) * 16;
  const int wid = tid >> 6, lane = tid & 63;
  const int wm = (wid >> 1) * 64, wn = (wid & 1) * 64;
  const int fr = lane & 15;
  const int fk = (lane >> 4) * 8;
  f32x4 acc[4][4] = {};

  for (int k0 = 0; k0 < K; k0 += 32) {
    __syncthreads();
    {
      float v[16];
      size_t g = (size_t)(m0 + srow) * K + k0 + skc;
      if (a_f32) {
        const float4* p = (const float4*)((const float*)A + g);
#pragma unroll
        for (int q = 0; q < 4; q++) {
          float4 t4 = p[q];
          v[4*q+0] = t4.x; v[4*q+1] = t4.y; v[4*q+2] = t4.z; v[4*q+3] = t4.w;
        }
      } else {
        const uint4* u = (const uint4*)((const bf16*)A + g);
        uint4 u0 = u[0], u1 = u[1];
        const bf16* c0 = (const bf16*)&u0; const bf16* c1 = (const bf16*)&u1;
#pragma unroll
        for (int q = 0; q < 8; q++) { v[q] = (float)c0[q]; v[8+q] = (float)c1[q]; }
      }
      bf16x8 h0, h1, l0, l1;
#pragma unroll
      for (int q = 0; q < 8; q++) {
        bf16 ha = (bf16)v[q], hb = (bf16)v[8+q];
        h0[q] = ha; h1[q] = hb;
        l0[q] = (bf16)(v[q]   - (float)ha);
        l1[q] = (bf16)(v[8+q] - (float)hb);
      }
      *(bf16x8*)&Ah[srow * LDT + skc]     = h0;
      *(bf16x8*)&Ah[srow * LDT + skc + 8] = h1;
      if (aLo) {
        *(bf16x8*)&Al[srow * LDT + skc]     = l0;
        *(bf16x8*)&Al[srow * LDT + skc + 8] = l1;
      }
    }
    {
      float v[16];
      size_t g = bwOff + (size_t)(n0 + srow) * K + k0 + skc;
      if (b_f32) {
        const float4* p = (const float4*)((const float*)Bw + g);
#pragma unroll
        for (int q = 0; q < 4; q++) {
          float4 t4 = p[q];
          v[4*q+0] = t4.x; v[4*q+1] = t4.y; v[4*q+2] = t4.z; v[4*q+3] = t4.w;
        }
      } else {
        const uint4* u = (const uint4*)((const bf16*)Bw + g);
        uint4 u0 = u[0], u1 = u[1];
        const bf16* c0 = (const bf16*)&u0; const bf16* c1 = (const bf16*)&u1;
#pragma unroll
        for (int q = 0; q < 8; q++) { v[q] = (float)c0[q]; v[8+q] = (float)c1[q]; }
      }
      bf16x8 h0, h1, l0, l1;
#pragma unroll
      for (int q = 0; q < 8; q++) {
        bf16 ha = (bf16)v[q], hb = (bf16)v[8+q];
        h0[q] = ha; h1[q] = hb;
        l0[q] = (bf16)(v[q]   - (float)ha);
        l1[q] = (bf16)(v[8+q] - (float)hb);
      }
      *(bf16x8*)&Bh[srow * LDT + skc]     = h0;
      *(bf16x8*)&Bh[srow * LDT + skc + 8] = h1;
      if (bLo) {
        *(bf16x8*)&Bl[srow * LDT + skc]     = l0;
        *(bf16x8*)&Bl[srow * LDT + skc + 8] = l1;
      }
    }
    __syncthreads();
    bf16x8 ah[4], bh[4];
#pragma unroll
    for (int i = 0; i < 4; i++) ah[i] = *(const bf16x8*)&Ah[(wm + i*16 + fr) * LDT + fk];
#pragma unroll
    for (int j = 0; j < 4; j++) bh[j] = *(const bf16x8*)&Bh[(wn + j*16 + fr) * LDT + fk];
#pragma unroll
    for (int i = 0; i < 4; i++)
#pragma unroll
      for (int j = 0; j < 4; j++)
        acc[i][j] = MFMA16(ah[i], bh[j], acc[i][j]);
    if (aLo) {
      bf16x8 al[4];
#pragma unroll
      for (int i = 0; i < 4; i++) al[i] = *(const bf16x8*)&Al[(wm + i*16 + fr) * LDT + fk];
#pragma unroll
      for (int i = 0; i < 4; i++)
#pragma unroll
        for (int j = 0; j < 4; j++)
          acc[i][j] = MFMA16(al[i], bh[j], acc[i][j]);
    }
    if (bLo) {
      bf16x8 bl[4];
#pragma unroll
      for (int j = 0; j < 4; j++) bl[j] = *(const bf16x8*)&Bl[(wn + j*16 + fr) * LDT + fk];
#pragma unroll
      for (int i = 0; i < 4; i++)
#pragma unroll
        for (int j = 0; j < 4; j++)
          acc[i][j] = MFMA16(ah[i], bl[j], acc[i][j]);
    }
  }
  const int orow0 = m0 + wm + (lane >> 4) * 4;
  const int ocol0 = n0 + wn + (lane & 15);
#pragma unroll
  for (int j = 0; j < 4; j++) {
    int col = ocol0 + j * 16;
    float bv = ldf(bias, biasOff + col, b_f32);
#pragma unroll
    for (int i = 0; i < 4; i++) {
#pragma unroll
      for (int r = 0; r < 4; r++) {
        float vv = acc[i][j][r] + bv;
        if (RELUF) vv = fmaxf(vv, 0.0f);
        Cf[(size_t)(orow0 + i * 16 + r) * N + col] = vv;
      }
    }
  }
}

// =====================================================================
// Prepass: split K (fp32, strided per-head rows) -> kh/kl bf16 [bh][s][64]
// grid (16 bh, 32 s-blocks of 64)
// =====================================================================
__global__ __launch_bounds__(256) void prep_split(const float* __restrict__ base, int ld, int ofs0,
                                                  bf16* __restrict__ oh, bf16* __restrict__ ol)
{
  const int bh = blockIdx.x, s0 = blockIdx.y * 64;
  const int b = bh >> 3, h = bh & 7, ofs = ofs0 + h * HD;
  const int tid = threadIdx.x;
#pragma unroll
  for (int it = 0; it < 16; ++it) {
    int idx = it * 256 + tid, r = idx >> 6, d = idx & 63;
    float v = base[(size_t)((s0 + r) * NB + b) * ld + ofs + d];
    bf16 hi = (bf16)v;
    size_t o = ((size_t)bh * T_SEQ + s0 + r) * 64 + d;
    oh[o] = hi; ol[o] = (bf16)(v - (float)hi);
  }
}

// =====================================================================
// Prepass: transpose+split V -> vth/vtl bf16 [bh][d][s]; also per-64-chunk
// column sums vcs[bh][chunk][d] (fp32). grid (16 bh, 16 s-blocks of 128)
// =====================================================================
__global__ __launch_bounds__(256) void prep_vt(const float* __restrict__ base, int ld, int ofs0,
                                               bf16* __restrict__ vth, bf16* __restrict__ vtl,
                                               float* __restrict__ vcs)
{
  __shared__ float ts[128 * 65];
  const int bh = blockIdx.x, s0 = blockIdx.y * 128;
  const int b = bh >> 3, h = bh & 7, ofs = ofs0 + h * HD;
  const int tid = threadIdx.x;
#pragma unroll
  for (int it = 0; it < 32; ++it) {
    int idx = it * 256 + tid, r = idx >> 6, d = idx & 63;
    ts[r * 65 + d] = base[(size_t)((s0 + r) * NB + b) * ld + ofs + d];
  }
  __syncthreads();
  const int d = tid >> 2, sseg = (tid & 3) * 32;
#pragma unroll
  for (int g = 0; g < 4; ++g) {
    bf16x8 hv, lv;
#pragma unroll
    for (int q = 0; q < 8; ++q) {
      float v = ts[(sseg + g * 8 + q) * 65 + d];
      bf16 hi = (bf16)v; hv[q] = hi; lv[q] = (bf16)(v - (float)hi);
    }
    size_t o = ((size_t)bh * 64 + d) * T_SEQ + s0 + sseg + g * 8;
    *(bf16x8*)&vth[o] = hv;
    *(bf16x8*)&vtl[o] = lv;
  }
  if (tid < 128) {
    int c = tid >> 6, dd = tid & 63;
    float s = 0.0f;
    for (int j = 0; j < 64; ++j) s += ts[(c * 64 + j) * 65 + dd];
    vcs[((size_t)bh * 32 + blockIdx.y * 2 + c) * 64 + dd] = s;
  }
}

// pair heavy/light causal blocks on the same CU
__device__ __forceinline__ int remap_ty(int ty) { return (ty < 16) ? ty : 47 - ty; }

// =====================================================================
// Pass 1: min/max of masked raw scores via MFMA (3-term split-bf16).
// grid (16 bh, 32 t-blocks of 64); partial[2*(by*16+bx)] = {min,max}
// =====================================================================
template<bool MASK>
__global__ __launch_bounds__(256) void mm_mfma(const float* __restrict__ qbase, int qld, int qofs0,
                                               const bf16* __restrict__ kh, const bf16* __restrict__ kl,
                                               float* __restrict__ partial)
{
  __shared__ __align__(16) bf16 Qh[64 * LDA], Ql[64 * LDA], Kh[64 * LDA], Kl[64 * LDA];
  __shared__ float rn[4], rx[4];
  const int bh = blockIdx.x, tyr = remap_ty(blockIdx.y);
  const int t0 = tyr * 64;
  const int b = bh >> 3, h = bh & 7;
  const int qofs = qofs0 + h * HD;
  const int tid = threadIdx.x;
#pragma unroll
  for (int it = 0; it < 16; ++it) {
    int idx = it * 256 + tid, r = idx >> 6, d = idx & 63;
    float v = qbase[(size_t)((t0 + r) * NB + b) * qld + qofs + d] * 0.125f;
    bf16 hi = (bf16)v;
    Qh[r * LDA + d] = hi; Ql[r * LDA + d] = (bf16)(v - (float)hi);
  }
  const int wid = tid >> 6, lane = tid & 63;
  const int wm_ = (wid >> 1) * 32, wn_ = (wid & 1) * 32;
  const int fr = lane & 15, fko = (lane >> 4) * 8;
  const int crr = (lane >> 4) * 4, crc = lane & 15;
  const int cr = tid >> 2, cseg = (tid & 3) * 16;
  float mn = 1e30f, mx = -1e30f;
  const int nch = MASK ? (tyr + 1) : 32;
  for (int sc = 0; sc < nch; ++sc) {
    const int s0 = sc * 64;
    __syncthreads();
    {
      size_t go = ((size_t)bh * T_SEQ + s0 + cr) * 64 + cseg;
      *(bf16x8*)&Kh[cr * LDA + cseg]     = *(const bf16x8*)&kh[go];
      *(bf16x8*)&Kh[cr * LDA + cseg + 8] = *(const bf16x8*)&kh[go + 8];
      *(bf16x8*)&Kl[cr * LDA + cseg]     = *(const bf16x8*)&kl[go];
      *(bf16x8*)&Kl[cr * LDA + cseg + 8] = *(const bf16x8*)&kl[go + 8];
    }
    __syncthreads();
    f32x4 a4[2][2] = {};
#pragma unroll
    for (int ks = 0; ks < 2; ++ks) {
      bf16x8 aH[2], aL[2], bH[2], bL[2];
#pragma unroll
      for (int i = 0; i < 2; ++i) {
        aH[i] = *(const bf16x8*)&Qh[(wm_ + i*16 + fr) * LDA + ks*32 + fko];
        aL[i] = *(const bf16x8*)&Ql[(wm_ + i*16 + fr) * LDA + ks*32 + fko];
        bH[i] = *(const bf16x8*)&Kh[(wn_ + i*16 + fr) * LDA + ks*32 + fko];
        bL[i] = *(const bf16x8*)&Kl[(wn_ + i*16 + fr) * LDA + ks*32 + fko];
      }
#pragma unroll
      for (int i = 0; i < 2; ++i)
#pragma unroll
        for (int j = 0; j < 2; ++j) {
          a4[i][j] = MFMA16(aH[i], bH[j], a4[i][j]);
          a4[i][j] = MFMA16(aL[i], bH[j], a4[i][j]);
          a4[i][j] = MFMA16(aH[i], bL[j], a4[i][j]);
        }
    }
#pragma unroll
    for (int i = 0; i < 2; ++i)
#pragma unroll
      for (int j = 0; j < 2; ++j)
#pragma unroll
        for (int r = 0; r < 4; ++r) {
          float w = a4[i][j][r];
          if (MASK) {
            int tg = t0 + wm_ + i*16 + crr + r;
            int sg = s0 + wn_ + j*16 + crc;
            if (sg > tg) w = 0.0f;      // w * tril: masked -> exact 0 (included in min/max)
          }
          mn = fminf(mn, w); mx = fmaxf(mx, w);
        }
  }
#pragma unroll
  for (int o = 32; o; o >>= 1) { mn = fminf(mn, __shfl_down(mn, o)); mx = fmaxf(mx, __shfl_down(mx, o)); }
  if (lane == 0) { rn[wid] = mn; rx[wid] = mx; }
  __syncthreads();
  if (tid == 0) {
    int bidx = blockIdx.y * NBH + blockIdx.x;
    partial[2 * bidx]     = fminf(fminf(rn[0], rn[1]), fminf(rn[2], rn[3]));
    partial[2 * bidx + 1] = fmaxf(fmaxf(rx[0], rx[1]), fmaxf(rx[2], rx[3]));
  }
}

// reduce 512 partial pairs -> mmf
__global__ __launch_bounds__(512) void reduce_mm(const float* __restrict__ partial,
                                                 float* __restrict__ mmf)
{
  const int tid = threadIdx.x, w = tid >> 6, l = tid & 63;
  __shared__ float rn[8], rx[8];
  float mn = partial[2 * tid], mx = partial[2 * tid + 1];
#pragma unroll
  for (int o = 32; o; o >>= 1) { mn = fminf(mn, __shfl_down(mn, o)); mx = fmaxf(mx, __shfl_down(mx, o)); }
  if (l == 0) { rn[w] = mn; rx[w] = mx; }
  __syncthreads();
  if (tid == 0) {
    float a = 1e30f, c = -1e30f;
#pragma unroll
    for (int i = 0; i < 8; i++) { a = fminf(a, rn[i]); c = fmaxf(c, rx[i]); }
    mmf[0] = a; mmf[1] = c;
  }
}

// =====================================================================
// Pass 2: out = sum_s ((w_m - mn)*inv) * v[s] via MFMA.
// Per-entry normalization in fp32 (mirrors reference); P split to bf16
// hi/lo through LDS; PV 3-term. Fully-masked tail chunks handled as
// (0-mn)*inv * colsum(V) from vcs. grid (16 bh, 32 t-blocks of 64)
// =====================================================================
template<bool MASK>
__global__ __launch_bounds__(256) void attn_mfma(const float* __restrict__ qbase, int qld, int qofs0,
                                                 const bf16* __restrict__ kh, const bf16* __restrict__ kl,
                                                 const bf16* __restrict__ vth, const bf16* __restrict__ vtl,
                                                 const float* __restrict__ vcs,
                                                 const float* __restrict__ mmf,
                                                 float* __restrict__ aout)
{
  __shared__ __align__(16) bf16 Qh[64 * LDA], Ql[64 * LDA];
  __shared__ __align__(16) bf16 Kh[64 * LDA], Kl[64 * LDA];
  __shared__ __align__(16) bf16 Vh[64 * LDA], Vl[64 * LDA];
  __shared__ __align__(16) bf16 Ph[64 * LDA], Pl[64 * LDA];
  const int bh = blockIdx.x, tyr = remap_ty(blockIdx.y);
  const int t0 = tyr * 64;
  const int b = bh >> 3, h = bh & 7;
  const int qofs = qofs0 + h * HD;
  const int tid = threadIdx.x;
  const float mn = mmf[0];
  const float inv = 1.0f / (mmf[1] - mmf[0]);
#pragma unroll
  for (int it = 0; it < 16; ++it) {
    int idx = it * 256 + tid, r = idx >> 6, d = idx & 63;
    float v = qbase[(size_t)((t0 + r) * NB + b) * qld + qofs + d] * 0.125f;
    bf16 hi = (bf16)v;
    Qh[r * LDA + d] = hi; Ql[r * LDA + d] = (bf16)(v - (float)hi);
  }
  const int wid = tid >> 6, lane = tid & 63;
  const int wm_ = (wid >> 1) * 32, wn_ = (wid & 1) * 32;
  const int fr = lane & 15, fko = (lane >> 4) * 8;
  const int crr = (lane >> 4) * 4, crc = lane & 15;
  const int cr = tid >> 2, cseg = (tid & 3) * 16;
  f32x4 o4[2][2] = {};
  const int nch = MASK ? (tyr + 1) : 32;
  for (int sc = 0; sc < nch; ++sc) {
    const int s0 = sc * 64;
    __syncthreads();
    {
      size_t go = ((size_t)bh * T_SEQ + s0 + cr) * 64 + cseg;
      *(bf16x8*)&Kh[cr * LDA + cseg]     = *(const bf16x8*)&kh[go];
      *(bf16x8*)&Kh[cr * LDA + cseg + 8] = *(const bf16x8*)&kh[go + 8];
      *(bf16x8*)&Kl[cr * LDA + cseg]     = *(const bf16x8*)&kl[go];
      *(bf16x8*)&Kl[cr * LDA + cseg + 8] = *(const bf16x8*)&kl[go + 8];
      size_t gv = ((size_t)bh * 64 + cr) * T_SEQ + s0 + cseg;   // cr = d-row
      *(bf16x8*)&Vh[cr * LDA + cseg]     = *(const bf16x8*)&vth[gv];
      *(bf16x8*)&Vh[cr * LDA + cseg + 8] = *(const bf16x8*)&vth[gv + 8];
      *(bf16x8*)&Vl[cr * LDA + cseg]     = *(const bf16x8*)&vtl[gv];
      *(bf16x8*)&Vl[cr * LDA + cseg + 8] = *(const bf16x8*)&vtl[gv + 8];
    }
    __syncthreads();
    f32x4 a4[2][2] = {};
#pragma unroll
    for (int ks = 0; ks < 2; ++ks) {
      bf16x8 aH[2], aL[2], bH[2], bL[2];
#pragma unroll
      for (int i = 0; i < 2; ++i) {
        aH[i] = *(const bf16x8*)&Qh[(wm_ + i*16 + fr) * LDA + ks*32 + fko];
        aL[i] = *(const bf16x8*)&Ql[(wm_ + i*16 + fr) * LDA + ks*32 + fko];
        bH[i] = *(const bf16x8*)&Kh[(wn_ + i*16 + fr) * LDA + ks*32 + fko];
        bL[i] = *(const bf16x8*)&Kl[(wn_ + i*16 + fr) * LDA + ks*32 + fko];
      }
#pragma unroll
      for (int i = 0; i < 2; ++i)
#pragma unroll
        for (int j = 0; j < 2; ++j) {
          a4[i][j] = MFMA16(aH[i], bH[j], a4[i][j]);
          a4[i][j] = MFMA16(aL[i], bH[j], a4[i][j]);
          a4[i][j] = MFMA16(aH[i], bL[j], a4[i][j]);
        }
    }
    // normalize + split -> P LDS
#pragma unroll
    for (int i = 0; i < 2; ++i)
#pragma unroll
      for (int j = 0; j < 2; ++j)
#pragma unroll
        for (int r = 0; r < 4; ++r) {
          int tl = wm_ + i*16 + crr + r;
          int sl = wn_ + j*16 + crc;
          float w = a4[i][j][r];
          if (MASK && (s0 + sl) > (t0 + tl)) w = 0.0f;
          float p = (w - mn) * inv;
          bf16 ph = (bf16)p;
          Ph[tl * LDA + sl] = ph;
          Pl[tl * LDA + sl] = (bf16)(p - (float)ph);
        }
    __syncthreads();
    // PV: A = P [t][s], B = V^T [d][s]
#pragma unroll
    for (int ks = 0; ks < 2; ++ks) {
      bf16x8 pH[2], pL[2], vH[2], vL[2];
#pragma unroll
      for (int i = 0; i < 2; ++i) {
        pH[i] = *(const bf16x8*)&Ph[(wm_ + i*16 + fr) * LDA + ks*32 + fko];
        pL[i] = *(const bf16x8*)&Pl[(wm_ + i*16 + fr) * LDA + ks*32 + fko];
        vH[i] = *(const bf16x8*)&Vh[(wn_ + i*16 + fr) * LDA + ks*32 + fko];
        vL[i] = *(const bf16x8*)&Vl[(wn_ + i*16 + fr) * LDA + ks*32 + fko];
      }
#pragma unroll
      for (int i = 0; i < 2; ++i)
#pragma unroll
        for (int j = 0; j < 2; ++j) {
          o4[i][j] = MFMA16(pH[i], vH[j], o4[i][j]);
          o4[i][j] = MFMA16(pL[i], vH[j], o4[i][j]);
          o4[i][j] = MFMA16(pH[i], vL[j], o4[i][j]);
        }
    }
  }
  // fully-masked tail: every entry is (0-mn)*inv -> rank-0 * colsum(V)
  if (MASK && nch < 32) {
    const float c = (0.0f - mn) * inv;
#pragma unroll
    for (int j = 0; j < 2; ++j) {
      float s = 0.0f;
      for (int ch = nch; ch < 32; ++ch)
        s += vcs[((size_t)bh * 32 + ch) * 64 + wn_ + j*16 + crc];
      float add = c * s;
#pragma unroll
      for (int i = 0; i < 2; ++i)
#pragma unroll
        for (int r = 0; r < 4; ++r) o4[i][j][r] += add;
    }
  }
#pragma unroll
  for (int i = 0; i < 2; ++i)
#pragma unroll
    for (int j = 0; j < 2; ++j)
#pragma unroll
      for (int r = 0; r < 4; ++r) {
        int tl = wm_ + i*16 + crr + r;
        int dl = wn_ + j*16 + crc;
        aout[(size_t)((t0 + tl) * NB + b) * CE + h * HD + dl] = o4[i][j][r];
      }
}

// =====================================================================
// LayerNorm(res + y)
// =====================================================================
__global__ __launch_bounds__(256) void ln32(const float* res, const float* yy,
                                            const void* __restrict__ g, const void* __restrict__ be,
                                            size_t goff, const int* __restrict__ flags,
                                            float* xfo)
{
  __shared__ float red[4];
  const bool fl = flags[0] != 0;
  const int tid = threadIdx.x;
  const size_t base = (size_t)blockIdx.x * CE;
  float a  = res[base + tid] + yy[base + tid];
  float b2 = res[base + tid + 256] + yy[base + tid + 256];
  float s = a + b2;
#pragma unroll
  for (int o = 32; o; o >>= 1) s += __shfl_down(s, o);
  if ((tid & 63) == 0) red[tid >> 6] = s;
  __syncthreads();
  float mu = (red[0] + red[1] + red[2] + red[3]) * (1.0f / 512.0f);
  __syncthreads();
  float da = a - mu, db = b2 - mu;
  float q = da * da + db * db;
#pragma unroll
  for (int o = 32; o; o >>= 1) q += __shfl_down(q, o);
  if ((tid & 63) == 0) red[tid >> 6] = q;
  __syncthreads();
  float var = (red[0] + red[1] + red[2] + red[3]) * (1.0f / 512.0f);
  float rs = rsqrtf(var + 1e-20f);
  xfo[base + tid]       = da * rs * ldf(g, goff + tid, fl)       + ldf(be, goff + tid, fl);
  xfo[base + tid + 256] = db * rs * ldf(g, goff + tid + 256, fl) + ldf(be, goff + tid + 256, fl);
}

// =====================================================================
extern "C" void kernel_launch(void* const* d_in, const int* in_sizes, int n_in,
                              void* d_out, int out_size, void* d_ws, size_t ws_size,
                              hipStream_t stream)
{
  (void)in_sizes; (void)n_in; (void)out_size; (void)ws_size;
  const void* x_in   = d_in[0];
  const void* enc_in = d_in[1];
  const int*  tokens = (const int*)d_in[2];
  const void* sWqkv = d_in[3];
  const void* sbqkv = d_in[4];
  const void* sWo   = d_in[5];
  const void* sbo   = d_in[6];
  const void* cWqkv = d_in[7];
  const void* cbqkv = d_in[8];
  const void* cWo   = d_in[9];
  const void* cbo   = d_in[10];
  const void* fc1w  = d_in[11];
  const void* fc1b  = d_in[12];
  const void* fc2w  = d_in[13];
  const void* fc2b  = d_in[14];
  const void* ln1g  = d_in[15];
  const void* ln1b  = d_in[16];
  const void* ln2g  = d_in[17];
  const void* ln2b  = d_in[18];
  const void* ln3g  = d_in[19];
  const void* ln3b  = d_in[20];

  char* ws = (char*)d_ws;
  size_t off = 0;
  auto alloc = [&](size_t bytes) -> char* {
    char* p = ws + off;
    off += (bytes + 255) & ~(size_t)255;
    return p;
  };
  // ~56.6 MiB total
  int*   flags   = (int*)  alloc(256);
  float* mmf     = (float*)alloc(256);
  float* partial = (float*)alloc(4096);
  float* xf      = (float*)alloc((size_t)ROWS * CE * 4);      //  8 MiB
  float* y       = (float*)alloc((size_t)ROWS * CE * 4);      //  8 MiB
  float* qkv     = (float*)alloc((size_t)ROWS * 1536 * 4);    // 24 MiB
  bf16*  khb     = (bf16*) alloc((size_t)16 * T_SEQ * 64 * 2); // 4 MiB
  bf16*  klb     = (bf16*) alloc((size_t)16 * T_SEQ * 64 * 2); // 4 MiB
  bf16*  vth     = (bf16*) alloc((size_t)16 * 64 * T_SEQ * 2); // 4 MiB
  bf16*  vtl     = (bf16*) alloc((size_t)16 * 64 * T_SEQ * 2); // 4 MiB
  float* vcs     = (float*)alloc((size_t)16 * 32 * 64 * 4);    // 128 KiB
  float* kvb = qkv + (size_t)ROWS * 512;

  sniff<<<1, 256, 0, stream>>>((const u16*)x_in, tokens, flags);
  posembed<<<ROWS, 256, 0, stream>>>(x_in, tokens, flags, xf);

  for (int l = 0; l < 4; l++) {
    // ---------------- self-attention ----------------
    gemm_mfma<false><<<dim3(12, 32), 256, 0, stream>>>(
        xf, 0, sWqkv, (size_t)l * 1536 * 512, sbqkv, (size_t)l * 1536, flags, qkv, ROWS, 1536, 512);
    prep_split<<<dim3(16, 32), 256, 0, stream>>>(qkv, 1536, 512, khb, klb);
    prep_vt<<<dim3(16, 16), 256, 0, stream>>>(qkv, 1536, 1024, vth, vtl, vcs);
    mm_mfma<true><<<dim3(NBH, 32), 256, 0, stream>>>(qkv, 1536, 0, khb, klb, partial);
    reduce_mm<<<1, 512, 0, stream>>>(partial, mmf);
    attn_mfma<true><<<dim3(NBH, 32), 256, 0, stream>>>(qkv, 1536, 0, khb, klb, vth, vtl, vcs, mmf, y);
    gemm_mfma<false><<<dim3(4, 32), 256, 0, stream>>>(
        y, 0, sWo, (size_t)l * 512 * 512, sbo, (size_t)l * 512, flags, qkv, ROWS, 512, 512);
    ln32<<<ROWS, 256, 0, stream>>>(xf, qkv, ln1g, ln1b, (size_t)l * 512, flags, xf);

    // ---------------- cross-attention ----------------
    gemm_mfma<false><<<dim3(4, 32), 256, 0, stream>>>(
        xf, 0, cWqkv, (size_t)l * 1536 * 512, cbqkv, (size_t)l * 1536, flags, qkv, ROWS, 512, 512);
    gemm_mfma<false><<<dim3(8, 32), 256, 0, stream>>>(
        enc_in, 1, cWqkv, (size_t)l * 1536 * 512 + (size_t)512 * 512, cbqkv, (size_t)l * 1536 + 512,
        flags, kvb, ROWS, 1024, 512);
    prep_split<<<dim3(16, 32), 256, 0, stream>>>(kvb, 1024, 0, khb, klb);
    prep_vt<<<dim3(16, 16), 256, 0, stream>>>(kvb, 1024, 512, vth, vtl, vcs);
    mm_mfma<false><<<dim3(NBH, 32), 256, 0, stream>>>(qkv, 512, 0, khb, klb, partial);
    reduce_mm<<<1, 512, 0, stream>>>(partial, mmf);
    attn_mfma<false><<<dim3(NBH, 32), 256, 0, stream>>>(qkv, 512, 0, khb, klb, vth, vtl, vcs, mmf, y);
    gemm_mfma<false><<<dim3(4, 32), 256, 0, stream>>>(
        y, 0, cWo, (size_t)l * 512 * 512, cbo, (size_t)l * 512, flags, qkv, ROWS, 512, 512);
    ln32<<<ROWS, 256, 0, stream>>>(xf, qkv, ln2g, ln2b, (size_t)l * 512, flags, xf);

    // ---------------- FFN ----------------
    for (int half = 0; half < 2; half++) {
      const float* Ain = xf + (size_t)half * 2048 * 512;
      float* yout = y + (size_t)half * 2048 * 512;
      gemm_mfma<true><<<dim3(16, 16), 256, 0, stream>>>(
          Ain, 0, fc1w, (size_t)l * 2048 * 512, fc1b, (size_t)l * 2048, flags, qkv, 2048, 2048, 512);
      gemm_mfma<false><<<dim3(4, 16), 256, 0, stream>>>(
          qkv, 0, fc2w, (size_t)l * 512 * 2048, fc2b, (size_t)l * 512, flags, yout, 2048, 512, 2048);
    }
    float* lnout = (l == 3) ? (float*)d_out : xf;
    ln32<<<ROWS, 256, 0, stream>>>(xf, y, ln3g, ln3b, (size_t)l * 512, flags, lnout);
  }
}